// Round 2
// baseline (5002.551 us; speedup 1.0000x reference)
//
#include <hip/hip_runtime.h>
#include <cstdint>

namespace {

constexpr int NHEADS = 12;
constexpr int TOT    = 138;   // sum of per-head output counts
constexpr int NLBL   = 30;
constexpr int HID    = 1024;
constexpr int KC     = 8;     // hidden chunk per inner iteration
constexpr int WROW   = 144;   // padded packed W row (64B-aligned rows)
constexpr int MAXO   = 19;
constexpr int KSPLIT = HID / 2;  // per-wave K range

constexpr int HOFF[NHEADS + 1] = {0, 9, 18, 25, 33, 42, 50, 66, 82, 95, 114, 129, 138};
constexpr int NI[NHEADS] = {9, 9, 7, 8, 9, 8, 16, 16, 13, 19, 15, 9};
constexpr int CAND[TOT] = {
    0, 1, 2, 3, 5, 7, 19, 20, 28,
    0, 1, 2, 3, 5, 7, 19, 20, 28,
    0, 5, 7, 18, 19, 20, 22,
    0, 1, 2, 3, 5, 7, 19, 20,
    0, 1, 2, 3, 5, 7, 19, 20, 28,
    0, 1, 2, 3, 5, 7, 9, 20,
    0, 2, 4, 6, 8, 10, 12, 13, 14, 15, 16, 17, 21, 24, 26, 27,
    0, 4, 6, 8, 10, 11, 12, 13, 14, 15, 17, 23, 24, 26, 27, 29,
    0, 4, 6, 10, 11, 14, 15, 17, 21, 24, 25, 26, 27,
    0, 4, 6, 7, 8, 10, 11, 12, 13, 14, 15, 17, 21, 23, 24, 26, 27, 28, 29,
    0, 4, 6, 8, 10, 11, 12, 13, 14, 15, 16, 17, 21, 27, 29,
    0, 4, 6, 10, 12, 15, 21, 24, 25};

__device__ __forceinline__ float fast_tanh(float x) {
    // tanh(x) = 1 - 2/(exp(2x)+1); v_exp_f32 + v_rcp_f32, graceful at +-inf
    float e = __expf(2.0f * x);
    return 1.0f - 2.0f * __builtin_amdgcn_rcpf(e + 1.0f);
}

}  // namespace

// ---------------------------------------------------------------------------
// Pack Ws [12][1024][19] -> Wp [1024][144] (k-major, heads concatenated, padded)
// so the hot loop reads one contiguous, 64B-aligned row per k (s_load-friendly:
// wave-uniform address, provably aligned).
// ---------------------------------------------------------------------------
__global__ void pack_w(const float* __restrict__ Ws, float* __restrict__ Wp) {
    int k = blockIdx.x;    // 0..1023
    int c = threadIdx.x;   // 0..143
    float v = 0.0f;
    if (c < TOT) {
        int i, base;
        if      (c <   9) { i = 0;  base = 0;   }
        else if (c <  18) { i = 1;  base = 9;   }
        else if (c <  25) { i = 2;  base = 18;  }
        else if (c <  33) { i = 3;  base = 25;  }
        else if (c <  42) { i = 4;  base = 33;  }
        else if (c <  50) { i = 5;  base = 42;  }
        else if (c <  66) { i = 6;  base = 50;  }
        else if (c <  82) { i = 7;  base = 66;  }
        else if (c <  95) { i = 8;  base = 82;  }
        else if (c < 114) { i = 9;  base = 95;  }
        else if (c < 129) { i = 10; base = 114; }
        else              { i = 11; base = 129; }
        v = Ws[((size_t)i * HID + k) * MAXO + (c - base)];
    }
    Wp[(size_t)k * WROW + c] = v;
}

// ---------------------------------------------------------------------------
// Main fused kernel. Block = 128 threads = 2 waves, owns 64 rows.
// Wave w accumulates k in [w*512, w*512+512) for its 64 rows (one row/lane,
// 138 fp32 accumulators in VGPRs, W rows via wave-uniform scalar loads).
// Wave 1 dumps partials to LDS; wave 0 combines and runs the epilogue:
// bias -> per-head weighted CE (wave-reduced, double atomics) ->
// head-selected scatter into [B,30] logits.
// ---------------------------------------------------------------------------
template <bool PACKED>
__global__ __launch_bounds__(128, 2)
void fused_main(const float* __restrict__ F,
                const float* __restrict__ W,    // Wp [1024][144] or raw Ws [12][1024][19]
                const float* __restrict__ bs,   // [12][19]
                const int* __restrict__ head_ids,
                const int* __restrict__ labels,
                float* __restrict__ out,        // d_out: [0] loss (finalize), [1..] logits
                double* __restrict__ partials)  // 24 doubles in d_ws
{
    const int tid  = threadIdx.x;
    const int wv   = tid >> 6;     // 0 or 1
    const int lane = tid & 63;
    const int row  = blockIdx.x * 64 + lane;
    const float* __restrict__ frow = F + (size_t)row * HID;

    const int kbeg = wv * KSPLIT;
    const int kend = kbeg + KSPLIT;

    float acc[TOT];
#pragma unroll
    for (int c = 0; c < TOT; ++c) acc[c] = 0.0f;

    __align__(16) float cur[KC], nxt[KC];
#pragma unroll
    for (int q = 0; q < KC / 4; ++q)
        *reinterpret_cast<float4*>(&cur[4 * q]) =
            *reinterpret_cast<const float4*>(frow + kbeg + 4 * q);

    for (int k0 = kbeg; k0 < kend; k0 += KC) {
        // register double-buffer prefetch of the next feature chunk
        if (k0 + KC < kend) {
#pragma unroll
            for (int q = 0; q < KC / 4; ++q)
                *reinterpret_cast<float4*>(&nxt[4 * q]) =
                    *reinterpret_cast<const float4*>(frow + k0 + KC + 4 * q);
        }
        float h[KC];
#pragma unroll
        for (int kk = 0; kk < KC; ++kk) h[kk] = fast_tanh(cur[kk]);

#pragma unroll
        for (int kk = 0; kk < KC; ++kk) {
            if (PACKED) {
                const float* __restrict__ wr = W + (size_t)(k0 + kk) * WROW;
#pragma unroll
                for (int c = 0; c < TOT; ++c) acc[c] = fmaf(h[kk], wr[c], acc[c]);
            } else {
#pragma unroll
                for (int i = 0; i < NHEADS; ++i) {
                    const float* __restrict__ wr = W + ((size_t)i * HID + (k0 + kk)) * MAXO;
#pragma unroll
                    for (int j = 0; j < MAXO; ++j)
                        if (j < NI[i]) acc[HOFF[i] + j] = fmaf(h[kk], wr[j], acc[HOFF[i] + j]);
                }
            }
        }
        if (k0 + KC < kend) {
#pragma unroll
            for (int kk = 0; kk < KC; ++kk) cur[kk] = nxt[kk];
        }
    }

    // ---- cross-wave combine: wave 1 -> LDS -> wave 0 ----
    // stride 139: 139 % 32 = 11, gcd(11,32) = 1 -> 2 lanes/bank = conflict-free
    constexpr int XST = TOT + 1;  // 139
    __shared__ float xch[64 * XST];
    if (wv == 1) {
#pragma unroll
        for (int c = 0; c < TOT; ++c) xch[lane * XST + c] = acc[c];
    }
    __syncthreads();
    if (wv != 0) return;

#pragma unroll
    for (int c = 0; c < TOT; ++c) acc[c] += xch[lane * XST + c];

    // bias
#pragma unroll
    for (int i = 0; i < NHEADS; ++i)
#pragma unroll
        for (int j = 0; j < MAXO; ++j)
            if (j < NI[i]) acc[HOFF[i] + j] += bs[i * MAXO + j];

    const int label = labels[row];
    const int head  = head_ids[row];

    // per-head weighted CE
    float wn[NHEADS], wd[NHEADS];
#pragma unroll
    for (int i = 0; i < NHEADS; ++i) {
        int y = 0;  // REMAP[i][label]: index of label in CAND, else 0
#pragma unroll
        for (int j = 0; j < MAXO; ++j)
            if (j < NI[i]) { if (CAND[HOFF[i] + j] == label) y = j; }

        float m = acc[HOFF[i]];
#pragma unroll
        for (int j = 1; j < MAXO; ++j)
            if (j < NI[i]) m = fmaxf(m, acc[HOFF[i] + j]);
        float s = 0.0f;
#pragma unroll
        for (int j = 0; j < MAXO; ++j)
            if (j < NI[i]) s += __expf(acc[HOFF[i] + j] - m);
        float lse = m + __logf(s);

        float ly = acc[HOFF[i]];  // compile-time-indexed select of acc[HOFF+y]
#pragma unroll
        for (int j = 1; j < MAXO; ++j)
            if (j < NI[i]) ly = (y == j) ? acc[HOFF[i] + j] : ly;

        float w = (y == 0) ? 0.05f : 1.0f;
        wn[i] = w * (lse - ly);
        wd[i] = w;
    }

    // wave reduction (64 lanes) + one double atomic per block per value
#pragma unroll
    for (int i = 0; i < NHEADS; ++i) {
#pragma unroll
        for (int off = 32; off >= 1; off >>= 1) {
            wn[i] += __shfl_xor(wn[i], off);
            wd[i] += __shfl_xor(wd[i], off);
        }
    }
    if (lane == 0) {
#pragma unroll
        for (int i = 0; i < NHEADS; ++i) {
            atomicAdd(&partials[2 * i],     (double)wn[i]);
            atomicAdd(&partials[2 * i + 1], (double)wd[i]);
        }
    }

    // head-selected scatter to 30-label space; per-lane direct stores
    // (writes are ~3% of traffic; contiguous region merges in L2)
    {
        float v[NLBL];
#pragma unroll
        for (int l = 0; l < NLBL; ++l) v[l] = 1e-7f;
#pragma unroll
        for (int i = 0; i < NHEADS; ++i) {
            if (head == i) {
#pragma unroll
                for (int j = 0; j < MAXO; ++j)
                    if (j < NI[i]) v[CAND[HOFF[i] + j]] = acc[HOFF[i] + j];
            }
        }
        float* __restrict__ dst = out + 1 + (size_t)row * NLBL;
#pragma unroll
        for (int l = 0; l < NLBL; ++l) dst[l] = v[l];
    }
}

__global__ void finalize(const double* __restrict__ partials, float* __restrict__ out) {
    double t = 0.0;
    for (int i = 0; i < NHEADS; ++i) t += partials[2 * i] / partials[2 * i + 1];
    out[0] = (float)t;
}

extern "C" void kernel_launch(void* const* d_in, const int* in_sizes, int n_in,
                              void* d_out, int out_size, void* d_ws, size_t ws_size,
                              hipStream_t stream) {
    const float* F        = (const float*)d_in[0];
    const float* Ws       = (const float*)d_in[1];
    const float* bs       = (const float*)d_in[2];
    const int*   head_ids = (const int*)d_in[3];
    const int*   labels   = (const int*)d_in[4];
    float* out = (float*)d_out;

    double* partials = (double*)d_ws;
    float*  Wp = (float*)((char*)d_ws + 256);
    const size_t need = 256 + (size_t)HID * WROW * sizeof(float);

    // d_ws is poisoned 0xAA before every launch — zero the loss accumulators
    hipMemsetAsync(d_ws, 0, 2 * NHEADS * sizeof(double), stream);

    const int B = in_sizes[3];  // 65536 (head_ids count)
    const int nblk = B / 64;

    if (ws_size >= need) {
        pack_w<<<HID, WROW, 0, stream>>>(Ws, Wp);
        fused_main<true><<<nblk, 128, 0, stream>>>(F, Wp, bs, head_ids, labels, out, partials);
    } else {
        fused_main<false><<<nblk, 128, 0, stream>>>(F, Ws, bs, head_ids, labels, out, partials);
    }
    finalize<<<1, 1, 0, stream>>>(partials, out);
}

// Round 3
// 1951.866 us; speedup vs baseline: 2.5630x; 2.5630x over previous
//
#include <hip/hip_runtime.h>
#include <cstdint>

namespace {

constexpr int NHEADS = 12;
constexpr int TOT    = 138;   // sum of per-head output counts
constexpr int NLBL   = 30;
constexpr int HID    = 1024;
constexpr int KC     = 8;     // hidden chunk per inner iteration
constexpr int WROW   = 144;   // padded packed W row (64B-aligned rows)
constexpr int MAXO   = 19;
constexpr int KSPLIT = HID / 2;  // per-wave K range

constexpr int HOFF[NHEADS + 1] = {0, 9, 18, 25, 33, 42, 50, 66, 82, 95, 114, 129, 138};
constexpr int NI[NHEADS] = {9, 9, 7, 8, 9, 8, 16, 16, 13, 19, 15, 9};
constexpr int CAND[TOT] = {
    0, 1, 2, 3, 5, 7, 19, 20, 28,
    0, 1, 2, 3, 5, 7, 19, 20, 28,
    0, 5, 7, 18, 19, 20, 22,
    0, 1, 2, 3, 5, 7, 19, 20,
    0, 1, 2, 3, 5, 7, 19, 20, 28,
    0, 1, 2, 3, 5, 7, 9, 20,
    0, 2, 4, 6, 8, 10, 12, 13, 14, 15, 16, 17, 21, 24, 26, 27,
    0, 4, 6, 8, 10, 11, 12, 13, 14, 15, 17, 23, 24, 26, 27, 29,
    0, 4, 6, 10, 11, 14, 15, 17, 21, 24, 25, 26, 27,
    0, 4, 6, 7, 8, 10, 11, 12, 13, 14, 15, 17, 21, 23, 24, 26, 27, 28, 29,
    0, 4, 6, 8, 10, 11, 12, 13, 14, 15, 16, 17, 21, 27, 29,
    0, 4, 6, 10, 12, 15, 21, 24, 25};

__device__ __forceinline__ float fast_tanh(float x) {
    // tanh(x) = 1 - 2/(exp(2x)+1); v_exp_f32 + v_rcp_f32, graceful at +-inf
    float e = __expf(2.0f * x);
    return 1.0f - 2.0f * __builtin_amdgcn_rcpf(e + 1.0f);
}

}  // namespace

// ---------------------------------------------------------------------------
// Pack Ws [12][1024][19] -> Wp [1024][144] (k-major, heads concatenated, padded)
// so the hot loop reads one contiguous, 64B-aligned row per k (s_load-friendly:
// wave-uniform address, provably aligned).
// ---------------------------------------------------------------------------
__global__ void pack_w(const float* __restrict__ Ws, float* __restrict__ Wp) {
    int k = blockIdx.x;    // 0..1023
    int c = threadIdx.x;   // 0..143
    float v = 0.0f;
    if (c < TOT) {
        int i, base;
        if      (c <   9) { i = 0;  base = 0;   }
        else if (c <  18) { i = 1;  base = 9;   }
        else if (c <  25) { i = 2;  base = 18;  }
        else if (c <  33) { i = 3;  base = 25;  }
        else if (c <  42) { i = 4;  base = 33;  }
        else if (c <  50) { i = 5;  base = 42;  }
        else if (c <  66) { i = 6;  base = 50;  }
        else if (c <  82) { i = 7;  base = 66;  }
        else if (c <  95) { i = 8;  base = 82;  }
        else if (c < 114) { i = 9;  base = 95;  }
        else if (c < 129) { i = 10; base = 114; }
        else              { i = 11; base = 129; }
        v = Ws[((size_t)i * HID + k) * MAXO + (c - base)];
    }
    Wp[(size_t)k * WROW + c] = v;
}

// ---------------------------------------------------------------------------
// Main fused kernel. Block = 128 threads = 2 waves, owns 64 rows.
// Wave w accumulates k in [w*512, w*512+512) for its 64 rows (one row/lane,
// 138 fp32 accumulators in VGPRs, W rows via wave-uniform scalar loads).
// Wave 1 dumps partials to LDS; wave 0 combines and runs the epilogue.
//
// __launch_bounds__(128, 1): min-waves=1 -> VGPR cap 512. Round-2 evidence:
// (128,2) clamped allocation to 128 VGPR and spilled ~70 accumulators ->
// 14 GB/dispatch of scratch traffic, VALUBusy 6%. This kernel NEEDS ~200 VGPR;
// residency is 2 waves/SIMD regardless (LDS: 35.8KB x 4 blocks/CU).
// ---------------------------------------------------------------------------
template <bool PACKED>
__global__ __launch_bounds__(128, 1)
void fused_main(const float* __restrict__ F,
                const float* __restrict__ W,    // Wp [1024][144] or raw Ws [12][1024][19]
                const float* __restrict__ bs,   // [12][19]
                const int* __restrict__ head_ids,
                const int* __restrict__ labels,
                float* __restrict__ out,        // d_out: [0] loss (finalize), [1..] logits
                double* __restrict__ partials)  // 24 doubles in d_ws
{
    const int tid  = threadIdx.x;
    const int wv   = tid >> 6;     // 0 or 1
    const int lane = tid & 63;
    const int row  = blockIdx.x * 64 + lane;
    const float* __restrict__ frow = F + (size_t)row * HID;

    const int kbeg = wv * KSPLIT;
    const int kend = kbeg + KSPLIT;

    float acc[TOT];
#pragma unroll
    for (int c = 0; c < TOT; ++c) acc[c] = 0.0f;

    __align__(16) float cur[KC], nxt[KC];
#pragma unroll
    for (int q = 0; q < KC / 4; ++q)
        *reinterpret_cast<float4*>(&cur[4 * q]) =
            *reinterpret_cast<const float4*>(frow + kbeg + 4 * q);

    for (int k0 = kbeg; k0 < kend; k0 += KC) {
        // register double-buffer prefetch of the next feature chunk
        if (k0 + KC < kend) {
#pragma unroll
            for (int q = 0; q < KC / 4; ++q)
                *reinterpret_cast<float4*>(&nxt[4 * q]) =
                    *reinterpret_cast<const float4*>(frow + k0 + KC + 4 * q);
        }
        float h[KC];
#pragma unroll
        for (int kk = 0; kk < KC; ++kk) h[kk] = fast_tanh(cur[kk]);

#pragma unroll
        for (int kk = 0; kk < KC; ++kk) {
            if (PACKED) {
                const float* __restrict__ wr = W + (size_t)(k0 + kk) * WROW;
#pragma unroll
                for (int c = 0; c < TOT; ++c) acc[c] = fmaf(h[kk], wr[c], acc[c]);
            } else {
#pragma unroll
                for (int i = 0; i < NHEADS; ++i) {
                    const float* __restrict__ wr = W + ((size_t)i * HID + (k0 + kk)) * MAXO;
#pragma unroll
                    for (int j = 0; j < MAXO; ++j)
                        if (j < NI[i]) acc[HOFF[i] + j] = fmaf(h[kk], wr[j], acc[HOFF[i] + j]);
                }
            }
        }
        if (k0 + KC < kend) {
#pragma unroll
            for (int kk = 0; kk < KC; ++kk) cur[kk] = nxt[kk];
        }
    }

    // ---- cross-wave combine: wave 1 -> LDS -> wave 0 ----
    // stride 139: 139 % 32 = 11, gcd(11,32) = 1 -> 2 lanes/bank = conflict-free
    constexpr int XST = TOT + 1;  // 139
    __shared__ float xch[64 * XST];
    if (wv == 1) {
#pragma unroll
        for (int c = 0; c < TOT; ++c) xch[lane * XST + c] = acc[c];
    }
    __syncthreads();
    if (wv != 0) return;

#pragma unroll
    for (int c = 0; c < TOT; ++c) acc[c] += xch[lane * XST + c];

    // bias
#pragma unroll
    for (int i = 0; i < NHEADS; ++i)
#pragma unroll
        for (int j = 0; j < MAXO; ++j)
            if (j < NI[i]) acc[HOFF[i] + j] += bs[i * MAXO + j];

    const int label = labels[row];
    const int head  = head_ids[row];

    // per-head weighted CE
    float wn[NHEADS], wd[NHEADS];
#pragma unroll
    for (int i = 0; i < NHEADS; ++i) {
        int y = 0;  // REMAP[i][label]: index of label in CAND, else 0
#pragma unroll
        for (int j = 0; j < MAXO; ++j)
            if (j < NI[i]) { if (CAND[HOFF[i] + j] == label) y = j; }

        float m = acc[HOFF[i]];
#pragma unroll
        for (int j = 1; j < MAXO; ++j)
            if (j < NI[i]) m = fmaxf(m, acc[HOFF[i] + j]);
        float s = 0.0f;
#pragma unroll
        for (int j = 0; j < MAXO; ++j)
            if (j < NI[i]) s += __expf(acc[HOFF[i] + j] - m);
        float lse = m + __logf(s);

        float ly = acc[HOFF[i]];  // compile-time-indexed select of acc[HOFF+y]
#pragma unroll
        for (int j = 1; j < MAXO; ++j)
            if (j < NI[i]) ly = (y == j) ? acc[HOFF[i] + j] : ly;

        float w = (y == 0) ? 0.05f : 1.0f;
        wn[i] = w * (lse - ly);
        wd[i] = w;
    }

    // wave reduction (64 lanes) + one double atomic per block per value
#pragma unroll
    for (int i = 0; i < NHEADS; ++i) {
#pragma unroll
        for (int off = 32; off >= 1; off >>= 1) {
            wn[i] += __shfl_xor(wn[i], off);
            wd[i] += __shfl_xor(wd[i], off);
        }
    }
    if (lane == 0) {
#pragma unroll
        for (int i = 0; i < NHEADS; ++i) {
            atomicAdd(&partials[2 * i],     (double)wn[i]);
            atomicAdd(&partials[2 * i + 1], (double)wd[i]);
        }
    }

    // head-selected scatter to 30-label space; per-lane direct stores
    // (writes are ~3% of traffic; contiguous region merges in L2)
    {
        float v[NLBL];
#pragma unroll
        for (int l = 0; l < NLBL; ++l) v[l] = 1e-7f;
#pragma unroll
        for (int i = 0; i < NHEADS; ++i) {
            if (head == i) {
#pragma unroll
                for (int j = 0; j < MAXO; ++j)
                    if (j < NI[i]) v[CAND[HOFF[i] + j]] = acc[HOFF[i] + j];
            }
        }
        float* __restrict__ dst = out + 1 + (size_t)row * NLBL;
#pragma unroll
        for (int l = 0; l < NLBL; ++l) dst[l] = v[l];
    }
}

__global__ void finalize(const double* __restrict__ partials, float* __restrict__ out) {
    double t = 0.0;
    for (int i = 0; i < NHEADS; ++i) t += partials[2 * i] / partials[2 * i + 1];
    out[0] = (float)t;
}

extern "C" void kernel_launch(void* const* d_in, const int* in_sizes, int n_in,
                              void* d_out, int out_size, void* d_ws, size_t ws_size,
                              hipStream_t stream) {
    const float* F        = (const float*)d_in[0];
    const float* Ws       = (const float*)d_in[1];
    const float* bs       = (const float*)d_in[2];
    const int*   head_ids = (const int*)d_in[3];
    const int*   labels   = (const int*)d_in[4];
    float* out = (float*)d_out;

    double* partials = (double*)d_ws;
    float*  Wp = (float*)((char*)d_ws + 256);
    const size_t need = 256 + (size_t)HID * WROW * sizeof(float);

    // d_ws is poisoned 0xAA before every launch — zero the loss accumulators
    hipMemsetAsync(d_ws, 0, 2 * NHEADS * sizeof(double), stream);

    const int B = in_sizes[3];  // 65536 (head_ids count)
    const int nblk = B / 64;

    if (ws_size >= need) {
        pack_w<<<HID, WROW, 0, stream>>>(Ws, Wp);
        fused_main<true><<<nblk, 128, 0, stream>>>(F, Wp, bs, head_ids, labels, out, partials);
    } else {
        fused_main<false><<<nblk, 128, 0, stream>>>(F, Ws, bs, head_ids, labels, out, partials);
    }
    finalize<<<1, 1, 0, stream>>>(partials, out);
}

// Round 4
// 654.563 us; speedup vs baseline: 7.6426x; 2.9819x over previous
//
#include <hip/hip_runtime.h>
#include <cstdint>

namespace {

constexpr int NHEADS = 12;
constexpr int TOT    = 138;   // sum of per-head output counts
constexpr int NLBL   = 30;
constexpr int HID    = 1024;
constexpr int WROW   = 144;   // packed W row (heads concatenated, zero-padded)
constexpr int MAXO   = 19;

constexpr int HOFF[NHEADS + 1] = {0, 9, 18, 25, 33, 42, 50, 66, 82, 95, 114, 129, 138};
constexpr int NI[NHEADS] = {9, 9, 7, 8, 9, 8, 16, 16, 13, 19, 15, 9};
constexpr int CAND[TOT] = {
    0, 1, 2, 3, 5, 7, 19, 20, 28,
    0, 1, 2, 3, 5, 7, 19, 20, 28,
    0, 5, 7, 18, 19, 20, 22,
    0, 1, 2, 3, 5, 7, 19, 20,
    0, 1, 2, 3, 5, 7, 19, 20, 28,
    0, 1, 2, 3, 5, 7, 9, 20,
    0, 2, 4, 6, 8, 10, 12, 13, 14, 15, 16, 17, 21, 24, 26, 27,
    0, 4, 6, 8, 10, 11, 12, 13, 14, 15, 17, 23, 24, 26, 27, 29,
    0, 4, 6, 10, 11, 14, 15, 17, 21, 24, 25, 26, 27,
    0, 4, 6, 7, 8, 10, 11, 12, 13, 14, 15, 17, 21, 23, 24, 26, 27, 28, 29,
    0, 4, 6, 8, 10, 11, 12, 13, 14, 15, 16, 17, 21, 27, 29,
    0, 4, 6, 10, 12, 15, 21, 24, 25};

__device__ __forceinline__ float fast_tanh(float x) {
    float e = __expf(2.0f * x);
    return 1.0f - 2.0f * __builtin_amdgcn_rcpf(e + 1.0f);
}

}  // namespace

// ---------------------------------------------------------------------------
// Pack Ws [12][1024][19] -> Wp [1024][144] (k-major, heads concatenated,
// zero-padded cols 138..143).
// ---------------------------------------------------------------------------
__global__ void pack_w(const float* __restrict__ Ws, float* __restrict__ Wp) {
    int k = blockIdx.x;    // 0..1023
    int c = threadIdx.x;   // 0..143
    float v = 0.0f;
    if (c < TOT) {
        int i, base;
        if      (c <   9) { i = 0;  base = 0;   }
        else if (c <  18) { i = 1;  base = 9;   }
        else if (c <  25) { i = 2;  base = 18;  }
        else if (c <  33) { i = 3;  base = 25;  }
        else if (c <  42) { i = 4;  base = 33;  }
        else if (c <  50) { i = 5;  base = 42;  }
        else if (c <  66) { i = 6;  base = 50;  }
        else if (c <  82) { i = 7;  base = 66;  }
        else if (c <  95) { i = 8;  base = 82;  }
        else if (c < 114) { i = 9;  base = 95;  }
        else if (c < 129) { i = 10; base = 114; }
        else              { i = 11; base = 129; }
        v = Ws[((size_t)i * HID + k) * MAXO + (c - base)];
    }
    Wp[(size_t)k * WROW + c] = v;
}

// ---------------------------------------------------------------------------
// Register-tiled fused kernel. Block = 256 threads (4 waves), output tile
// 128 rows x 144 cols, thread tile 8x9 = 72 fp32 accumulators.
// K staged in LDS tiles of KB=16 (h transposed [k][132], w [k][16x12-padded]),
// with register prefetch of the next tile overlapping compute (T14).
// Epilogue: acc -> LDS [128][150] -> 128 threads own one full row each:
// bias + per-head weighted CE (wave-reduced, double atomics) + logits scatter.
// Round-3 lesson: 1 row/lane with 1:1 W-load:FMA was latency-bound (VALU 21%).
// ---------------------------------------------------------------------------
__global__ __launch_bounds__(256, 2)
void fused_tiled(const float* __restrict__ F,
                 const float* __restrict__ Wp,   // [1024][144]
                 const float* __restrict__ bs,   // [12][19]
                 const int* __restrict__ head_ids,
                 const int* __restrict__ labels,
                 float* __restrict__ out,        // [0] loss (finalize), [1..] logits
                 double* __restrict__ partials)  // 24 doubles in d_ws
{
    constexpr int KB  = 16;   // k per tile
    constexpr int TM  = 8, TN = 9;
    constexpr int HTS = 132;  // h-tile row stride (words): [KB][HTS]
    constexpr int WTS = 192;  // w-tile row stride: 16 groups * 12 words
    constexpr int EPS = 150;  // epilogue row stride
    constexpr int NT  = HID / KB;  // 64 tiles

    __shared__ __align__(16) char smem_raw[128 * EPS * 4];  // 76800 B
    float* const ht = (float*)smem_raw;                        // 8448 B
    float* const wt = (float*)(smem_raw + KB * HTS * 4);       // 12288 B
    float* const ep = (float*)smem_raw;                        // epilogue alias
    static_assert(KB * HTS * 4 + KB * WTS * 4 <= 128 * EPS * 4, "lds");

    const int tid  = threadIdx.x;
    const int tr   = tid & 15;   // thread-row group: rows tr*8..tr*8+7
    const int tc   = tid >> 4;   // thread-col group: cols tc*9..tc*9+8
    const int brow = blockIdx.x * 128;

    // staging mapping: thread loads rows sr and sr+64, k-cols k0+skq*4..+4
    const int sr  = tid >> 2;    // 0..63
    const int skq = tid & 3;     // 0..3
    const float* __restrict__ fptr = F + (size_t)(brow + sr) * HID + skq * 4;

    float acc[TM][TN];
#pragma unroll
    for (int m = 0; m < TM; ++m)
#pragma unroll
        for (int n = 0; n < TN; ++n) acc[m][n] = 0.0f;

    // prologue: load tile 0 into registers
    float4 ha = *(const float4*)(fptr);
    float4 hb = *(const float4*)(fptr + (size_t)64 * HID);
    float wv9[9];
#pragma unroll
    for (int j = 0; j < 9; ++j) wv9[j] = Wp[tid * 9 + j];

#pragma unroll 1
    for (int t = 0; t < NT; ++t) {
        __syncthreads();  // previous tile's LDS reads complete
        // ---- write staged regs -> LDS (tanh applied here, once per element)
#pragma unroll
        for (int j = 0; j < 4; ++j) {
            const int kl = skq * 4 + j;
            ht[kl * HTS + sr]      = fast_tanh(((const float*)&ha)[j]);
            ht[kl * HTS + sr + 64] = fast_tanh(((const float*)&hb)[j]);
        }
        // w: flat f = tid*9+j  ==  kl=tc, group=tr, off=j (144 = 16*9)
#pragma unroll
        for (int j = 0; j < 9; ++j)
            wt[tc * WTS + tr * 12 + j] = wv9[j];
        __syncthreads();  // LDS tile ready

        // ---- prefetch next tile into registers (latency hides under compute)
        if (t < NT - 1) {
            const float* __restrict__ fp = fptr + (t + 1) * KB;
            ha = *(const float4*)(fp);
            hb = *(const float4*)(fp + (size_t)64 * HID);
            const float* __restrict__ wp0 = Wp + (size_t)(t + 1) * KB * WROW;
#pragma unroll
            for (int j = 0; j < 9; ++j) wv9[j] = wp0[tid * 9 + j];
        }

        // ---- compute: 16 k-steps, 72 FMAs each
        const float* __restrict__ hp = ht + tr * TM;
        const float* __restrict__ wp = wt + tc * 12;
#pragma unroll
        for (int k = 0; k < KB; ++k) {
            float hr[TM];
            *(float4*)&hr[0] = *(const float4*)(hp + k * HTS);
            *(float4*)&hr[4] = *(const float4*)(hp + k * HTS + 4);
            float wr[TN];
            *(float4*)&wr[0] = *(const float4*)(wp + k * WTS);
            *(float4*)&wr[4] = *(const float4*)(wp + k * WTS + 4);
            wr[8] = (wp + k * WTS)[8];
#pragma unroll
            for (int m = 0; m < TM; ++m)
#pragma unroll
                for (int n = 0; n < TN; ++n)
                    acc[m][n] = fmaf(hr[m], wr[n], acc[m][n]);
        }
    }

    // ---- epilogue: acc tile -> LDS, then one thread per row
    __syncthreads();  // all compute reads of staging LDS done
#pragma unroll
    for (int m = 0; m < TM; ++m)
#pragma unroll
        for (int n = 0; n < TN; ++n)
            ep[(tr * TM + m) * EPS + tc * TN + n] = acc[m][n];
    __syncthreads();

    if (tid >= 128) return;
    const int r   = tid;          // row within block
    const int row = brow + r;

    float a[TOT];
#pragma unroll
    for (int c = 0; c < TOT; ++c) a[c] = ep[r * EPS + c];

    // bias
#pragma unroll
    for (int i = 0; i < NHEADS; ++i)
#pragma unroll
        for (int j = 0; j < MAXO; ++j)
            if (j < NI[i]) a[HOFF[i] + j] += bs[i * MAXO + j];

    const int label = labels[row];
    const int head  = head_ids[row];

    // per-head weighted CE
    float wn[NHEADS], wd[NHEADS];
#pragma unroll
    for (int i = 0; i < NHEADS; ++i) {
        int y = 0;
#pragma unroll
        for (int j = 0; j < MAXO; ++j)
            if (j < NI[i]) { if (CAND[HOFF[i] + j] == label) y = j; }

        float m = a[HOFF[i]];
#pragma unroll
        for (int j = 1; j < MAXO; ++j)
            if (j < NI[i]) m = fmaxf(m, a[HOFF[i] + j]);
        float s = 0.0f;
#pragma unroll
        for (int j = 0; j < MAXO; ++j)
            if (j < NI[i]) s += __expf(a[HOFF[i] + j] - m);
        float lse = m + __logf(s);

        float ly = a[HOFF[i]];
#pragma unroll
        for (int j = 1; j < MAXO; ++j)
            if (j < NI[i]) ly = (y == j) ? a[HOFF[i] + j] : ly;

        float w = (y == 0) ? 0.05f : 1.0f;
        wn[i] = w * (lse - ly);
        wd[i] = w;
    }

    // wave reduction (64 lanes; waves 0 and 1 handle rows 0..63 / 64..127)
#pragma unroll
    for (int i = 0; i < NHEADS; ++i) {
#pragma unroll
        for (int off = 32; off >= 1; off >>= 1) {
            wn[i] += __shfl_xor(wn[i], off);
            wd[i] += __shfl_xor(wd[i], off);
        }
    }
    if ((tid & 63) == 0) {
#pragma unroll
        for (int i = 0; i < NHEADS; ++i) {
            atomicAdd(&partials[2 * i],     (double)wn[i]);
            atomicAdd(&partials[2 * i + 1], (double)wd[i]);
        }
    }

    // head-selected scatter to 30-label space
    {
        float v[NLBL];
#pragma unroll
        for (int l = 0; l < NLBL; ++l) v[l] = 1e-7f;
#pragma unroll
        for (int i = 0; i < NHEADS; ++i) {
            if (head == i) {
#pragma unroll
                for (int j = 0; j < MAXO; ++j)
                    if (j < NI[i]) v[CAND[HOFF[i] + j]] = a[HOFF[i] + j];
            }
        }
        float* __restrict__ dst = out + 1 + (size_t)row * NLBL;
#pragma unroll
        for (int l = 0; l < NLBL; ++l) dst[l] = v[l];
    }
}

// ---------------------------------------------------------------------------
// Fallback (round-3 kernel, validated): used only if d_ws can't hold Wp.
// ---------------------------------------------------------------------------
__global__ __launch_bounds__(128, 1)
void fused_fallback(const float* __restrict__ F,
                    const float* __restrict__ W,  // raw Ws [12][1024][19]
                    const float* __restrict__ bs,
                    const int* __restrict__ head_ids,
                    const int* __restrict__ labels,
                    float* __restrict__ out,
                    double* __restrict__ partials)
{
    constexpr int KC = 8;
    constexpr int KSPLIT = HID / 2;
    const int tid  = threadIdx.x;
    const int wv   = tid >> 6;
    const int lane = tid & 63;
    const int row  = blockIdx.x * 64 + lane;
    const float* __restrict__ frow = F + (size_t)row * HID;

    const int kbeg = wv * KSPLIT, kend = kbeg + KSPLIT;

    float acc[TOT];
#pragma unroll
    for (int c = 0; c < TOT; ++c) acc[c] = 0.0f;

    __align__(16) float cur[KC], nxt[KC];
#pragma unroll
    for (int q = 0; q < KC / 4; ++q)
        *reinterpret_cast<float4*>(&cur[4 * q]) =
            *reinterpret_cast<const float4*>(frow + kbeg + 4 * q);

    for (int k0 = kbeg; k0 < kend; k0 += KC) {
        if (k0 + KC < kend) {
#pragma unroll
            for (int q = 0; q < KC / 4; ++q)
                *reinterpret_cast<float4*>(&nxt[4 * q]) =
                    *reinterpret_cast<const float4*>(frow + k0 + KC + 4 * q);
        }
        float h[KC];
#pragma unroll
        for (int kk = 0; kk < KC; ++kk) h[kk] = fast_tanh(cur[kk]);
#pragma unroll
        for (int kk = 0; kk < KC; ++kk) {
#pragma unroll
            for (int i = 0; i < NHEADS; ++i) {
                const float* __restrict__ wr = W + ((size_t)i * HID + (k0 + kk)) * MAXO;
#pragma unroll
                for (int j = 0; j < MAXO; ++j)
                    if (j < NI[i]) acc[HOFF[i] + j] = fmaf(h[kk], wr[j], acc[HOFF[i] + j]);
            }
        }
        if (k0 + KC < kend) {
#pragma unroll
            for (int kk = 0; kk < KC; ++kk) cur[kk] = nxt[kk];
        }
    }

    constexpr int XST = TOT + 1;
    __shared__ float xch[64 * XST];
    if (wv == 1) {
#pragma unroll
        for (int c = 0; c < TOT; ++c) xch[lane * XST + c] = acc[c];
    }
    __syncthreads();
    if (wv != 0) return;
#pragma unroll
    for (int c = 0; c < TOT; ++c) acc[c] += xch[lane * XST + c];

#pragma unroll
    for (int i = 0; i < NHEADS; ++i)
#pragma unroll
        for (int j = 0; j < MAXO; ++j)
            if (j < NI[i]) acc[HOFF[i] + j] += bs[i * MAXO + j];

    const int label = labels[row];
    const int head  = head_ids[row];
    float wn[NHEADS], wd[NHEADS];
#pragma unroll
    for (int i = 0; i < NHEADS; ++i) {
        int y = 0;
#pragma unroll
        for (int j = 0; j < MAXO; ++j)
            if (j < NI[i]) { if (CAND[HOFF[i] + j] == label) y = j; }
        float m = acc[HOFF[i]];
#pragma unroll
        for (int j = 1; j < MAXO; ++j)
            if (j < NI[i]) m = fmaxf(m, acc[HOFF[i] + j]);
        float s = 0.0f;
#pragma unroll
        for (int j = 0; j < MAXO; ++j)
            if (j < NI[i]) s += __expf(acc[HOFF[i] + j] - m);
        float lse = m + __logf(s);
        float ly = acc[HOFF[i]];
#pragma unroll
        for (int j = 1; j < MAXO; ++j)
            if (j < NI[i]) ly = (y == j) ? acc[HOFF[i] + j] : ly;
        float w = (y == 0) ? 0.05f : 1.0f;
        wn[i] = w * (lse - ly);
        wd[i] = w;
    }
#pragma unroll
    for (int i = 0; i < NHEADS; ++i) {
#pragma unroll
        for (int off = 32; off >= 1; off >>= 1) {
            wn[i] += __shfl_xor(wn[i], off);
            wd[i] += __shfl_xor(wd[i], off);
        }
    }
    if (lane == 0) {
#pragma unroll
        for (int i = 0; i < NHEADS; ++i) {
            atomicAdd(&partials[2 * i],     (double)wn[i]);
            atomicAdd(&partials[2 * i + 1], (double)wd[i]);
        }
    }
    {
        float v[NLBL];
#pragma unroll
        for (int l = 0; l < NLBL; ++l) v[l] = 1e-7f;
#pragma unroll
        for (int i = 0; i < NHEADS; ++i) {
            if (head == i) {
#pragma unroll
                for (int j = 0; j < MAXO; ++j)
                    if (j < NI[i]) v[CAND[HOFF[i] + j]] = acc[HOFF[i] + j];
            }
        }
        float* __restrict__ dst = out + 1 + (size_t)row * NLBL;
#pragma unroll
        for (int l = 0; l < NLBL; ++l) dst[l] = v[l];
    }
}

__global__ void finalize(const double* __restrict__ partials, float* __restrict__ out) {
    double t = 0.0;
    for (int i = 0; i < NHEADS; ++i) t += partials[2 * i] / partials[2 * i + 1];
    out[0] = (float)t;
}

extern "C" void kernel_launch(void* const* d_in, const int* in_sizes, int n_in,
                              void* d_out, int out_size, void* d_ws, size_t ws_size,
                              hipStream_t stream) {
    const float* F        = (const float*)d_in[0];
    const float* Ws       = (const float*)d_in[1];
    const float* bs       = (const float*)d_in[2];
    const int*   head_ids = (const int*)d_in[3];
    const int*   labels   = (const int*)d_in[4];
    float* out = (float*)d_out;

    double* partials = (double*)d_ws;
    float*  Wp = (float*)((char*)d_ws + 256);
    const size_t need = 256 + (size_t)HID * WROW * sizeof(float);

    hipMemsetAsync(d_ws, 0, 2 * NHEADS * sizeof(double), stream);

    const int B = in_sizes[3];  // 65536

    if (ws_size >= need) {
        pack_w<<<HID, WROW, 0, stream>>>(Ws, Wp);
        fused_tiled<<<B / 128, 256, 0, stream>>>(F, Wp, bs, head_ids, labels, out, partials);
    } else {
        fused_fallback<<<B / 64, 128, 0, stream>>>(F, Ws, bs, head_ids, labels, out, partials);
    }
    finalize<<<1, 1, 0, stream>>>(partials, out);
}

// Round 5
// 495.133 us; speedup vs baseline: 10.1034x; 1.3220x over previous
//
#include <hip/hip_runtime.h>
#include <cstdint>

typedef __attribute__((ext_vector_type(8)))  __bf16 bf16x8;
typedef __attribute__((ext_vector_type(16))) float  f32x16;

namespace {

constexpr int NHEADS = 12;
constexpr int TOT    = 138;   // sum of per-head output counts
constexpr int NLBL   = 30;
constexpr int HID    = 1024;
constexpr int MAXO   = 19;
constexpr int NPAD   = 160;   // padded col count = 5 N-tiles of 32
constexpr int KB     = 16;    // k per MFMA instruction / staged tile
constexpr int NT     = HID / KB;       // 64 k-tiles
constexpr int TILE_ELE = NPAD * KB;    // 2560 elements per k-tile per plane
constexpr int EPS    = 161;   // epilogue LDS row stride (161 mod 32 = 1 -> 2-way free)

constexpr int HOFF[NHEADS + 1] = {0, 9, 18, 25, 33, 42, 50, 66, 82, 95, 114, 129, 138};
constexpr int NI[NHEADS] = {9, 9, 7, 8, 9, 8, 16, 16, 13, 19, 15, 9};
constexpr int CAND[TOT] = {
    0, 1, 2, 3, 5, 7, 19, 20, 28,
    0, 1, 2, 3, 5, 7, 19, 20, 28,
    0, 5, 7, 18, 19, 20, 22,
    0, 1, 2, 3, 5, 7, 19, 20,
    0, 1, 2, 3, 5, 7, 19, 20, 28,
    0, 1, 2, 3, 5, 7, 9, 20,
    0, 2, 4, 6, 8, 10, 12, 13, 14, 15, 16, 17, 21, 24, 26, 27,
    0, 4, 6, 8, 10, 11, 12, 13, 14, 15, 17, 23, 24, 26, 27, 29,
    0, 4, 6, 10, 11, 14, 15, 17, 21, 24, 25, 26, 27,
    0, 4, 6, 7, 8, 10, 11, 12, 13, 14, 15, 17, 21, 23, 24, 26, 27, 28, 29,
    0, 4, 6, 8, 10, 11, 12, 13, 14, 15, 16, 17, 21, 27, 29,
    0, 4, 6, 10, 12, 15, 21, 24, 25};

__device__ __forceinline__ float fast_tanh(float x) {
    float e = __expf(2.0f * x);
    return 1.0f - 2.0f * __builtin_amdgcn_rcpf(e + 1.0f);
}

__device__ __forceinline__ void head_of(int c, int& i, int& base) {
    if      (c <   9) { i = 0;  base = 0;   }
    else if (c <  18) { i = 1;  base = 9;   }
    else if (c <  25) { i = 2;  base = 18;  }
    else if (c <  33) { i = 3;  base = 25;  }
    else if (c <  42) { i = 4;  base = 33;  }
    else if (c <  50) { i = 5;  base = 42;  }
    else if (c <  66) { i = 6;  base = 50;  }
    else if (c <  82) { i = 7;  base = 66;  }
    else if (c <  95) { i = 8;  base = 82;  }
    else if (c < 114) { i = 9;  base = 95;  }
    else if (c < 129) { i = 10; base = 114; }
    else              { i = 11; base = 129; }
}

}  // namespace

// ---------------------------------------------------------------------------
// Pack Ws [12][1024][19] -> split-bf16 planes Wh/Wl, layout [64 k-tiles]
// [160 cols][16 k] so a wave's B-fragment (col = lane&31, k = (lane>>5)*8+j)
// is one contiguous 16B load per N-tile per plane. Cols 138..159 zero-padded.
// ---------------------------------------------------------------------------
__global__ void pack_w_split(const float* __restrict__ Ws,
                             __bf16* __restrict__ Wh, __bf16* __restrict__ Wl) {
    const int t = blockIdx.x;  // k-tile 0..63
    for (int e = threadIdx.x; e < TILE_ELE; e += 256) {
        const int c  = e >> 4;
        const int kk = e & 15;
        float w = 0.0f;
        if (c < TOT) {
            int i, base;
            head_of(c, i, base);
            w = Ws[((size_t)i * HID + t * KB + kk) * MAXO + (c - base)];
        }
        __bf16 hi = (__bf16)w;
        Wh[(size_t)t * TILE_ELE + e] = hi;
        Wl[(size_t)t * TILE_ELE + e] = (__bf16)(w - (float)hi);
    }
}

// ---------------------------------------------------------------------------
// MFMA fused kernel. Block = 128 threads = 2 waves; block owns 128 rows.
// Wave w: rows w*64..w*64+63 as 2 M-tiles of 32; cols 0..159 as 5 N-tiles.
// Split-bf16: acc += Ah*Bh + Al*Bh + Ah*Bl  (3x mfma_f32_32x32x16_bf16 per
// (M,N,k-tile)) -> fp32-equivalent accuracy.
// h staged in LDS (tanh+split at stage time); B-fragments read directly from
// global (640 KB, L2-resident). F and B register double-buffered, prefetch
// issued before the staging barriers (T14).
// Round-4 lessons: fp32 path was LDS-BW-bound (VALU 40%, 2.6e7 conflicts);
// per-lane strided logit stores caused 8x write amplification (57 MB).
// ---------------------------------------------------------------------------
__global__ __launch_bounds__(128, 1)
void fused_mfma(const float* __restrict__ F,
                const __bf16* __restrict__ Wph,  // [64][160][16] hi plane
                const __bf16* __restrict__ Wpl,  // [64][160][16] lo plane
                const float* __restrict__ bs,    // [12][19]
                const int* __restrict__ head_ids,
                const int* __restrict__ labels,
                float* __restrict__ out,         // [0] loss (finalize), [1..] logits
                double* __restrict__ partials)   // 24 doubles in d_ws
{
    __shared__ __align__(16) __bf16 htH[128 * KB];   // 4096 B
    __shared__ __align__(16) __bf16 htL[128 * KB];   // 4096 B
    __shared__ __align__(16) float  ep[64 * EPS];    // 41216 B
    __shared__ float zbuf[64 * NLBL];                // 7680 B

    const int tid  = threadIdx.x;
    const int wv   = tid >> 6;
    const int lane = tid & 63;
    const int brow = blockIdx.x * 128;

    // staging: thread stages row (brow + tid), 16 k per tile
    const float* __restrict__ frow = F + (size_t)(brow + tid) * HID;
    // B-fragment lane offset within a k-tile plane: col=lane&31, k-half=lane>>5
    const int boff = (lane & 31) * KB + (lane >> 5) * 8;

    f32x16 acc[2][5];
#pragma unroll
    for (int mt = 0; mt < 2; ++mt)
#pragma unroll
        for (int n = 0; n < 5; ++n)
#pragma unroll
            for (int r = 0; r < 16; ++r) acc[mt][n][r] = 0.0f;

    float4 fbA[4], fbB[4];
    bf16x8 BhA[5], BlA[5], BhB[5], BlB[5];

    // prologue: tile 0 into the A-set
    {
        const float4* fp = (const float4*)frow;
#pragma unroll
        for (int q = 0; q < 4; ++q) fbA[q] = fp[q];
#pragma unroll
        for (int n = 0; n < 5; ++n) {
            BhA[n] = *(const bf16x8*)(Wph + boff + n * 512);
            BlA[n] = *(const bf16x8*)(Wpl + boff + n * 512);
        }
    }

// One pipeline step: prefetch tile T+1 into (FN,BHN,BLN); stage+compute tile T
// from (FC,BHC,BLC). Prefetch issued BEFORE barriers so latency spans
// staging + both barriers + MFMAs.
#define STEP(FC, BHC, BLC, FN, BHN, BLN, T)                                    \
    {                                                                          \
        if ((T) + 1 < NT) {                                                    \
            const float4* fp_ = (const float4*)(frow + ((T) + 1) * KB);        \
            _Pragma("unroll") for (int q = 0; q < 4; ++q) FN[q] = fp_[q];      \
            const size_t wo_ = (size_t)((T) + 1) * TILE_ELE + boff;            \
            _Pragma("unroll") for (int n = 0; n < 5; ++n) {                    \
                BHN[n] = *(const bf16x8*)(Wph + wo_ + n * 512);                \
                BLN[n] = *(const bf16x8*)(Wpl + wo_ + n * 512);                \
            }                                                                  \
        }                                                                      \
        __syncthreads(); /* previous tile's A-frag reads done */               \
        {                                                                      \
            bf16x8 vh0, vh1, vl0, vl1;                                         \
            _Pragma("unroll") for (int q = 0; q < 4; ++q) {                    \
                float vx[4] = {FC[q].x, FC[q].y, FC[q].z, FC[q].w};            \
                _Pragma("unroll") for (int e = 0; e < 4; ++e) {                \
                    const int j = q * 4 + e;                                   \
                    float hv = fast_tanh(vx[e]);                               \
                    __bf16 hh = (__bf16)hv;                                    \
                    __bf16 hl = (__bf16)(hv - (float)hh);                      \
                    if (j < 8) { vh0[j] = hh; vl0[j] = hl; }                   \
                    else       { vh1[j - 8] = hh; vl1[j - 8] = hl; }           \
                }                                                              \
            }                                                                  \
            *(bf16x8*)&htH[tid * KB]     = vh0;                                \
            *(bf16x8*)&htH[tid * KB + 8] = vh1;                                \
            *(bf16x8*)&htL[tid * KB]     = vl0;                                \
            *(bf16x8*)&htL[tid * KB + 8] = vl1;                                \
        }                                                                      \
        __syncthreads(); /* h tile ready */                                    \
        _Pragma("unroll") for (int mt = 0; mt < 2; ++mt) {                     \
            const int ab_ = (wv * 64 + mt * 32 + (lane & 31)) * KB +           \
                            (lane >> 5) * 8;                                   \
            bf16x8 ah = *(const bf16x8*)&htH[ab_];                             \
            bf16x8 al = *(const bf16x8*)&htL[ab_];                             \
            _Pragma("unroll") for (int n = 0; n < 5; ++n) {                    \
                acc[mt][n] = __builtin_amdgcn_mfma_f32_32x32x16_bf16(          \
                    ah, BHC[n], acc[mt][n], 0, 0, 0);                          \
                acc[mt][n] = __builtin_amdgcn_mfma_f32_32x32x16_bf16(          \
                    al, BHC[n], acc[mt][n], 0, 0, 0);                          \
                acc[mt][n] = __builtin_amdgcn_mfma_f32_32x32x16_bf16(          \
                    ah, BLC[n], acc[mt][n], 0, 0, 0);                          \
            }                                                                  \
        }                                                                      \
    }

    for (int t = 0; t < NT; t += 2) {
        STEP(fbA, BhA, BlA, fbB, BhB, BlB, t);
        STEP(fbB, BhB, BlB, fbA, BhA, BlA, t + 1);
    }
#undef STEP

    // ---- epilogue: two 64-row passes through LDS ----
    // C/D layout (m101-verified): col = lane&31, row = (reg&3)+8*(reg>>2)+4*(lane>>5)
    float wnacc[NHEADS], wdacc[NHEADS];
#pragma unroll
    for (int i = 0; i < NHEADS; ++i) { wnacc[i] = 0.0f; wdacc[i] = 0.0f; }

#pragma unroll 1
    for (int pass = 0; pass < 2; ++pass) {
        __syncthreads();  // ep/zbuf free (also covers K-loop tail)
        if (wv == pass) {
#pragma unroll
            for (int mt = 0; mt < 2; ++mt)
#pragma unroll
                for (int n = 0; n < 5; ++n)
#pragma unroll
                    for (int r = 0; r < 16; ++r) {
                        const int rl = mt * 32 + (r & 3) + 8 * (r >> 2) + 4 * (lane >> 5);
                        ep[rl * EPS + n * 32 + (lane & 31)] = acc[mt][n][r];
                    }
        }
        __syncthreads();

        if (tid < 64) {
            const int row = brow + pass * 64 + tid;
            float a[TOT];
#pragma unroll
            for (int c = 0; c < TOT; ++c) a[c] = ep[tid * EPS + c];

            // bias
#pragma unroll
            for (int i = 0; i < NHEADS; ++i)
#pragma unroll
                for (int j = 0; j < MAXO; ++j)
                    if (j < NI[i]) a[HOFF[i] + j] += bs[i * MAXO + j];

            const int label = labels[row];
            const int head  = head_ids[row];

#pragma unroll
            for (int i = 0; i < NHEADS; ++i) {
                int y = 0;
#pragma unroll
                for (int j = 0; j < MAXO; ++j)
                    if (j < NI[i]) { if (CAND[HOFF[i] + j] == label) y = j; }

                float m = a[HOFF[i]];
#pragma unroll
                for (int j = 1; j < MAXO; ++j)
                    if (j < NI[i]) m = fmaxf(m, a[HOFF[i] + j]);
                float s = 0.0f;
#pragma unroll
                for (int j = 0; j < MAXO; ++j)
                    if (j < NI[i]) s += __expf(a[HOFF[i] + j] - m);
                float lse = m + __logf(s);

                float ly = a[HOFF[i]];
#pragma unroll
                for (int j = 1; j < MAXO; ++j)
                    if (j < NI[i]) ly = (y == j) ? a[HOFF[i] + j] : ly;

                float w = (y == 0) ? 0.05f : 1.0f;
                wnacc[i] += w * (lse - ly);
                wdacc[i] += w;
            }

            // head-selected scatter into zbuf (LDS; global write staged below)
            float v[NLBL];
#pragma unroll
            for (int l = 0; l < NLBL; ++l) v[l] = 1e-7f;
#pragma unroll
            for (int i = 0; i < NHEADS; ++i) {
                if (head == i) {
#pragma unroll
                    for (int j = 0; j < MAXO; ++j)
                        if (j < NI[i]) v[CAND[HOFF[i] + j]] = a[HOFF[i] + j];
                }
            }
#pragma unroll
            for (int l = 0; l < NLBL; ++l) zbuf[tid * NLBL + l] = v[l];
        }
        __syncthreads();

        // coalesced logit store: 64 rows x 30 floats, consecutive dwords
        float* __restrict__ dst = out + 1 + (size_t)(brow + pass * 64) * NLBL;
        for (int q = tid; q < 64 * NLBL; q += 128) dst[q] = zbuf[q];
    }

    // loss reduction: wave 0 holds both passes' contributions
    if (tid < 64) {
#pragma unroll
        for (int i = 0; i < NHEADS; ++i) {
#pragma unroll
            for (int off = 32; off >= 1; off >>= 1) {
                wnacc[i] += __shfl_xor(wnacc[i], off);
                wdacc[i] += __shfl_xor(wdacc[i], off);
            }
        }
        if (tid == 0) {
#pragma unroll
            for (int i = 0; i < NHEADS; ++i) {
                atomicAdd(&partials[2 * i],     (double)wnacc[i]);
                atomicAdd(&partials[2 * i + 1], (double)wdacc[i]);
            }
        }
    }
}

// ---------------------------------------------------------------------------
// Fallback (round-3 kernel, validated): used only if d_ws can't hold W planes.
// ---------------------------------------------------------------------------
__global__ __launch_bounds__(128, 1)
void fused_fallback(const float* __restrict__ F,
                    const float* __restrict__ W,  // raw Ws [12][1024][19]
                    const float* __restrict__ bs,
                    const int* __restrict__ head_ids,
                    const int* __restrict__ labels,
                    float* __restrict__ out,
                    double* __restrict__ partials)
{
    constexpr int KC = 8;
    constexpr int KSPLIT = HID / 2;
    const int tid  = threadIdx.x;
    const int wv   = tid >> 6;
    const int lane = tid & 63;
    const int row  = blockIdx.x * 64 + lane;
    const float* __restrict__ frow = F + (size_t)row * HID;

    const int kbeg = wv * KSPLIT, kend = kbeg + KSPLIT;

    float acc[TOT];
#pragma unroll
    for (int c = 0; c < TOT; ++c) acc[c] = 0.0f;

    __align__(16) float cur[KC], nxt[KC];
#pragma unroll
    for (int q = 0; q < KC / 4; ++q)
        *reinterpret_cast<float4*>(&cur[4 * q]) =
            *reinterpret_cast<const float4*>(frow + kbeg + 4 * q);

    for (int k0 = kbeg; k0 < kend; k0 += KC) {
        if (k0 + KC < kend) {
#pragma unroll
            for (int q = 0; q < KC / 4; ++q)
                *reinterpret_cast<float4*>(&nxt[4 * q]) =
                    *reinterpret_cast<const float4*>(frow + k0 + KC + 4 * q);
        }
        float h[KC];
#pragma unroll
        for (int kk = 0; kk < KC; ++kk) h[kk] = fast_tanh(cur[kk]);
#pragma unroll
        for (int kk = 0; kk < KC; ++kk) {
#pragma unroll
            for (int i = 0; i < NHEADS; ++i) {
                const float* __restrict__ wr = W + ((size_t)i * HID + (k0 + kk)) * MAXO;
#pragma unroll
                for (int j = 0; j < MAXO; ++j)
                    if (j < NI[i]) acc[HOFF[i] + j] = fmaf(h[kk], wr[j], acc[HOFF[i] + j]);
            }
        }
        if (k0 + KC < kend) {
#pragma unroll
            for (int kk = 0; kk < KC; ++kk) cur[kk] = nxt[kk];
        }
    }

    constexpr int XST = TOT + 1;
    __shared__ float xch[64 * XST];
    if (wv == 1) {
#pragma unroll
        for (int c = 0; c < TOT; ++c) xch[lane * XST + c] = acc[c];
    }
    __syncthreads();
    if (wv != 0) return;
#pragma unroll
    for (int c = 0; c < TOT; ++c) acc[c] += xch[lane * XST + c];

#pragma unroll
    for (int i = 0; i < NHEADS; ++i)
#pragma unroll
        for (int j = 0; j < MAXO; ++j)
            if (j < NI[i]) acc[HOFF[i] + j] += bs[i * MAXO + j];

    const int label = labels[row];
    const int head  = head_ids[row];
    float wn[NHEADS], wd[NHEADS];
#pragma unroll
    for (int i = 0; i < NHEADS; ++i) {
        int y = 0;
#pragma unroll
        for (int j = 0; j < MAXO; ++j)
            if (j < NI[i]) { if (CAND[HOFF[i] + j] == label) y = j; }
        float m = acc[HOFF[i]];
#pragma unroll
        for (int j = 1; j < MAXO; ++j)
            if (j < NI[i]) m = fmaxf(m, acc[HOFF[i] + j]);
        float s = 0.0f;
#pragma unroll
        for (int j = 0; j < MAXO; ++j)
            if (j < NI[i]) s += __expf(acc[HOFF[i] + j] - m);
        float lse = m + __logf(s);
        float ly = acc[HOFF[i]];
#pragma unroll
        for (int j = 1; j < MAXO; ++j)
            if (j < NI[i]) ly = (y == j) ? acc[HOFF[i] + j] : ly;
        float w = (y == 0) ? 0.05f : 1.0f;
        wn[i] = w * (lse - ly);
        wd[i] = w;
    }
#pragma unroll
    for (int i = 0; i < NHEADS; ++i) {
#pragma unroll
        for (int off = 32; off >= 1; off >>= 1) {
            wn[i] += __shfl_xor(wn[i], off);
            wd[i] += __shfl_xor(wd[i], off);
        }
    }
    if (lane == 0) {
#pragma unroll
        for (int i = 0; i < NHEADS; ++i) {
            atomicAdd(&partials[2 * i],     (double)wn[i]);
            atomicAdd(&partials[2 * i + 1], (double)wd[i]);
        }
    }
    {
        float v[NLBL];
#pragma unroll
        for (int l = 0; l < NLBL; ++l) v[l] = 1e-7f;
#pragma unroll
        for (int i = 0; i < NHEADS; ++i) {
            if (head == i) {
#pragma unroll
                for (int j = 0; j < MAXO; ++j)
                    if (j < NI[i]) v[CAND[HOFF[i] + j]] = acc[HOFF[i] + j];
            }
        }
        float* __restrict__ dst = out + 1 + (size_t)row * NLBL;
#pragma unroll
        for (int l = 0; l < NLBL; ++l) dst[l] = v[l];
    }
}

__global__ void finalize(const double* __restrict__ partials, float* __restrict__ out) {
    double t = 0.0;
    for (int i = 0; i < NHEADS; ++i) t += partials[2 * i] / partials[2 * i + 1];
    out[0] = (float)t;
}

extern "C" void kernel_launch(void* const* d_in, const int* in_sizes, int n_in,
                              void* d_out, int out_size, void* d_ws, size_t ws_size,
                              hipStream_t stream) {
    const float* F        = (const float*)d_in[0];
    const float* Ws       = (const float*)d_in[1];
    const float* bs       = (const float*)d_in[2];
    const int*   head_ids = (const int*)d_in[3];
    const int*   labels   = (const int*)d_in[4];
    float* out = (float*)d_out;

    double* partials = (double*)d_ws;
    const size_t plane_bytes = (size_t)NT * TILE_ELE * sizeof(__bf16);  // 327680
    __bf16* Wph = (__bf16*)((char*)d_ws + 256);
    __bf16* Wpl = (__bf16*)((char*)d_ws + 256 + plane_bytes);
    const size_t need = 256 + 2 * plane_bytes;

    // d_ws poisoned 0xAA before every launch — zero the loss accumulators
    hipMemsetAsync(d_ws, 0, 2 * NHEADS * sizeof(double), stream);

    const int B = in_sizes[3];  // 65536

    if (ws_size >= need) {
        pack_w_split<<<NT, 256, 0, stream>>>(Ws, Wph, Wpl);
        fused_mfma<<<B / 128, 128, 0, stream>>>(F, Wph, Wpl, bs, head_ids, labels, out, partials);
    } else {
        fused_fallback<<<B / 64, 128, 0, stream>>>(F, Ws, bs, head_ids, labels, out, partials);
    }
    finalize<<<1, 1, 0, stream>>>(partials, out);
}